// Round 2
// baseline (1086.693 us; speedup 1.0000x reference)
//
#include <hip/hip_runtime.h>
#include <stdint.h>

// B=16, S=2048, D=128 attention: scores/inv_scale[b,q], softmax, JAX
// threefry dropout (key 42, p=0.1, PARTITIONABLE path), @ V.  fp32 round.
//
// RNG model (modern JAX, jax_threefry_partitionable=True, default >=0.4.36):
//   counts = iota(uint64, n); per element j: threefry2x32(key=(0,42),
//   x=(hi32(j), lo32(j))) -> (o1, o2); 32-bit bits = o1 ^ o2   [candidate A]
//   uniform = bitcast((bits>>9)|0x3F800000) - 1.0; keep = u < keep_prob.
// Fallback candidates if absmax ~5 again: bits = o2 (B), bits = o1 (C).

#define B_ 16
#define S_ 2048
#define D_ 128
#define TQ 32
#define TK 32
#define KSTRIDE 132   // 128 + 4 pad: 16B-aligned float4 rows, de-aligned banks
#define PSTRIDE 33

// threefry2x32, 20 rounds, key = (0, 42)
__device__ __forceinline__ uint2 threefry2x32_0_42(uint32_t x0, uint32_t x1) {
  const uint32_t k0 = 0u, k1 = 42u;
  const uint32_t k2 = 0x1BD11BDAu ^ k0 ^ k1;
  x0 += k0; x1 += k1;
#define TFR(r) { x0 += x1; x1 = (x1 << (r)) | (x1 >> (32 - (r))); x1 ^= x0; }
  TFR(13) TFR(15) TFR(26) TFR(6)
  x0 += k1; x1 += k2 + 1u;
  TFR(17) TFR(29) TFR(16) TFR(24)
  x0 += k2; x1 += k0 + 2u;
  TFR(13) TFR(15) TFR(26) TFR(6)
  x0 += k0; x1 += k1 + 3u;
  TFR(17) TFR(29) TFR(16) TFR(24)
  x0 += k1; x1 += k2 + 4u;
  TFR(13) TFR(15) TFR(26) TFR(6)
  x0 += k2; x1 += k0 + 5u;
#undef TFR
  return make_uint2(x0, x1);
}

// Partitionable-path 32-bit random bits for flat index j (< 2^32 here).
__device__ __forceinline__ uint32_t jax_random_bits32(uint32_t j) {
  const uint2 tf = threefry2x32_0_42(0u, j);
  return tf.x ^ tf.y;            // candidate A: xor of the two output words
}

__global__ __launch_bounds__(256, 2)
void attn_dropout_kernel(const float* __restrict__ q,
                         const float* __restrict__ kk,
                         const float* __restrict__ vv,
                         const float* __restrict__ inv_scale,
                         const float* __restrict__ dropout_p,
                         float* __restrict__ out) {
  __shared__ float sQ[TQ * KSTRIDE];
  __shared__ float sK[TK * KSTRIDE];
  __shared__ float sV[TK * KSTRIDE];
  __shared__ float sP[TQ * PSTRIDE];

  const int t  = threadIdx.x;
  const int b  = blockIdx.y;
  const int q0 = blockIdx.x * TQ;
  const int r  = t >> 3;   // query row within tile: 0..31 (8 lanes per row)
  const int g  = t & 7;    // lane-in-row: 0..7

  const float kp     = 1.0f - dropout_p[0];
  const float rscale = 1.0f / inv_scale[b * S_ + q0 + r];

  // ---- stage Q tile (TQ x D = 1024 float4, 4 per thread), coalesced ----
  {
    const float4* gq = (const float4*)(q + (size_t)(b * S_ + q0) * D_);
    #pragma unroll
    for (int i = 0; i < 4; ++i) {
      const int f = t + 256 * i;
      const int row = f >> 5, c4 = f & 31;
      *(float4*)&sQ[row * KSTRIDE + c4 * 4] = gq[row * 32 + c4];
    }
  }

  float m = -INFINITY, l = 0.0f;
  float4 o[4];
  #pragma unroll
  for (int i = 0; i < 4; ++i) o[i] = make_float4(0.f, 0.f, 0.f, 0.f);

  // flat dropout-mask index base for this row: j = b*S*S + q*S + k
  const uint32_t jrow = (uint32_t)b * (uint32_t)(S_ * S_)
                      + (uint32_t)(q0 + r) * (uint32_t)S_;

  for (int kt = 0; kt < S_ / TK; ++kt) {
    __syncthreads();   // previous PV done reading sV/sP before overwrite
    // ---- stage K,V tiles (each 1024 float4, 4 per thread), coalesced ----
    {
      const float4* gk = (const float4*)(kk + (size_t)(b * S_ + kt * TK) * D_);
      const float4* gv = (const float4*)(vv + (size_t)(b * S_ + kt * TK) * D_);
      #pragma unroll
      for (int i = 0; i < 4; ++i) {
        const int f = t + 256 * i;
        const int row = f >> 5, c4 = f & 31;
        *(float4*)&sK[row * KSTRIDE + c4 * 4] = gk[row * 32 + c4];
        *(float4*)&sV[row * KSTRIDE + c4 * 4] = gv[row * 32 + c4];
      }
    }
    __syncthreads();

    // ---- QK^T: thread computes 4 keys {g, g+8, g+16, g+24} for row r ----
    float acc[4] = {0.f, 0.f, 0.f, 0.f};
    {
      const float* qrow = &sQ[r * KSTRIDE];
      #pragma unroll 8
      for (int dc = 0; dc < 32; ++dc) {
        const float4 qv = *(const float4*)&qrow[dc * 4];
        #pragma unroll
        for (int j = 0; j < 4; ++j) {
          const float4 kv = *(const float4*)&sK[(g + 8 * j) * KSTRIDE + dc * 4];
          acc[j] += qv.x * kv.x + qv.y * kv.y + qv.z * kv.z + qv.w * kv.w;
        }
      }
    }
    #pragma unroll
    for (int j = 0; j < 4; ++j) acc[j] *= rscale;

    // ---- online softmax over the 8 lanes holding this row's 32 keys ----
    float mloc = fmaxf(fmaxf(acc[0], acc[1]), fmaxf(acc[2], acc[3]));
    #pragma unroll
    for (int off = 1; off < 8; off <<= 1)
      mloc = fmaxf(mloc, __shfl_xor(mloc, off, 8));
    const float mnew  = fmaxf(m, mloc);
    const float alpha = __expf(m - mnew);   // m=-inf first iter -> 0
    float p[4], lloc = 0.f;
    #pragma unroll
    for (int j = 0; j < 4; ++j) { p[j] = __expf(acc[j] - mnew); lloc += p[j]; }
    #pragma unroll
    for (int off = 1; off < 8; off <<= 1)
      lloc += __shfl_xor(lloc, off, 8);
    l = l * alpha + lloc;    // denominator WITHOUT dropout (matches reference)
    m = mnew;
    #pragma unroll
    for (int i = 0; i < 4; ++i) {
      o[i].x *= alpha; o[i].y *= alpha; o[i].z *= alpha; o[i].w *= alpha;
    }

    // ---- dropout (JAX partitionable threefry) + masked P to LDS ----
    #pragma unroll
    for (int j = 0; j < 4; ++j) {
      const uint32_t jf   = jrow + (uint32_t)(kt * TK + g + 8 * j);
      const uint32_t bits = jax_random_bits32(jf);
      const float u = __uint_as_float((bits >> 9) | 0x3F800000u) - 1.0f;
      sP[r * PSTRIDE + g + 8 * j] = (u < kp) ? p[j] : 0.0f;
    }
    __syncthreads();

    // ---- PV: O[r][4g+32i] += P[r][key] * V[key][4g+32i] ----
    #pragma unroll 4
    for (int key = 0; key < TK; ++key) {
      const float pw = sP[r * PSTRIDE + key];
      #pragma unroll
      for (int i = 0; i < 4; ++i) {
        const float4 vvv = *(const float4*)&sV[key * KSTRIDE + g * 4 + 32 * i];
        o[i].x += pw * vvv.x; o[i].y += pw * vvv.y;
        o[i].z += pw * vvv.z; o[i].w += pw * vvv.w;
      }
    }
  }

  // ---- epilogue: O / (l * keep_prob), coalesced float4 stores ----
  const float inv = 1.0f / (l * kp);
  float* orow = out + (size_t)(b * S_ + q0 + r) * D_ + g * 4;
  #pragma unroll
  for (int i = 0; i < 4; ++i) {
    float4 ov;
    ov.x = o[i].x * inv; ov.y = o[i].y * inv;
    ov.z = o[i].z * inv; ov.w = o[i].w * inv;
    *(float4*)(orow + 32 * i) = ov;
  }
}

extern "C" void kernel_launch(void* const* d_in, const int* in_sizes, int n_in,
                              void* d_out, int out_size, void* d_ws, size_t ws_size,
                              hipStream_t stream) {
  const float* q   = (const float*)d_in[0];
  const float* k   = (const float*)d_in[1];
  const float* v   = (const float*)d_in[2];
  const float* isf = (const float*)d_in[3];
  const float* dp  = (const float*)d_in[4];
  float* out = (float*)d_out;

  dim3 grid(S_ / TQ, B_);
  attn_dropout_kernel<<<grid, dim3(256), 0, stream>>>(q, k, v, isf, dp, out);
}

// Round 3
// 345.159 us; speedup vs baseline: 3.1484x; 3.1484x over previous
//
#include <hip/hip_runtime.h>
#include <stdint.h>

// B=16, S=2048, D=128 attention, per-query scale, softmax, exact JAX
// partitionable-threefry dropout (key 42, p=0.1), @V.
// MFMA round: split-bf16 (hi/lo) QK^T (3 MFMA products -> ~fp32 scores),
// bf16 P and V for PV.  Layouts per m89/m120-verified gfx950 mappings:
//   A[m][k]: m=lane&15, k=(lane>>4)*8+j   (16x16x32 bf16)
//   B[k][n]: n=lane&15, k=(lane>>4)*8+j
//   C/D    : col=lane&15, row=(lane>>4)*4+reg

#define B_ 16
#define S_ 2048
#define D_ 128
#define TQ 64     // q rows per block (4 waves x 16)
#define TK 64     // keys per iteration
#define KSTR 136  // bf16 stride for K rows (128+8): 272B = 17*16 -> aligned, 2-way banks
#define VSTR 72   // bf16 stride for V^T rows (64+8): 144B = 9*16
#define PSTR 72   // bf16 stride for P rows

typedef float f32x4 __attribute__((ext_vector_type(4)));
typedef short b16x8 __attribute__((ext_vector_type(8)));

// threefry2x32, 20 rounds, key = (0, 42)  [jax.random.key(42)]
__device__ __forceinline__ uint2 threefry2x32_0_42(uint32_t x0, uint32_t x1) {
  const uint32_t k0 = 0u, k1 = 42u;
  const uint32_t k2 = 0x1BD11BDAu ^ k0 ^ k1;
  x0 += k0; x1 += k1;
#define TFR(r) { x0 += x1; x1 = (x1 << (r)) | (x1 >> (32 - (r))); x1 ^= x0; }
  TFR(13) TFR(15) TFR(26) TFR(6)
  x0 += k1; x1 += k2 + 1u;
  TFR(17) TFR(29) TFR(16) TFR(24)
  x0 += k2; x1 += k0 + 2u;
  TFR(13) TFR(15) TFR(26) TFR(6)
  x0 += k0; x1 += k1 + 3u;
  TFR(17) TFR(29) TFR(16) TFR(24)
  x0 += k1; x1 += k2 + 4u;
  TFR(13) TFR(15) TFR(26) TFR(6)
  x0 += k2; x1 += k0 + 5u;
#undef TFR
  return make_uint2(x0, x1);
}

// HW-verified (round 2): partitionable path, counter (0, j), xor-fold.
__device__ __forceinline__ uint32_t jax_bits(uint32_t j) {
  const uint2 tf = threefry2x32_0_42(0u, j);
  return tf.x ^ tf.y;
}

__device__ __forceinline__ uint16_t bf16_rne(float x) {
  const uint32_t u = __float_as_uint(x);
  return (uint16_t)((u + 0x7FFFu + ((u >> 16) & 1u)) >> 16);
}

__global__ __launch_bounds__(256, 2)
void attn_mfma_kernel(const float* __restrict__ Q, const float* __restrict__ K,
                      const float* __restrict__ V, const float* __restrict__ ISF,
                      const float* __restrict__ DP, float* __restrict__ OUT) {
  __shared__ __align__(16) short sKhi[TK * KSTR];
  __shared__ __align__(16) short sKlo[TK * KSTR];
  __shared__ __align__(16) short sVT[D_ * VSTR];
  __shared__ __align__(16) short sP[4 * 16 * PSTR];   // per-wave 16x72

  const int t    = threadIdx.x;
  const int w    = t >> 6;
  const int lane = t & 63;
  const int l15  = lane & 15;
  const int quad = lane >> 4;
  const int b    = blockIdx.y;
  const int qw   = blockIdx.x * TQ + w * 16;   // wave's first q row

  const float kp = 1.0f - DP[0];

  float rsc[4], m_[4], l_[4];
  uint32_t jq[4];
  #pragma unroll
  for (int r = 0; r < 4; ++r) {
    rsc[r] = 1.0f / ISF[b * S_ + qw + quad * 4 + r];
    m_[r] = -INFINITY;
    l_[r] = 0.0f;
    jq[r] = ((uint32_t)b << 22) + (uint32_t)(qw + quad * 4 + r) * (uint32_t)S_;
  }

  // ---- Q fragments (hi/lo split), loaded once from global ----
  b16x8 qhi[4], qlo[4];
  {
    const float* qp = Q + ((size_t)(b * S_ + qw + l15)) * D_;
    #pragma unroll
    for (int c = 0; c < 4; ++c) {
      const float4 a = *(const float4*)(qp + c * 32 + quad * 8);
      const float4 d = *(const float4*)(qp + c * 32 + quad * 8 + 4);
      const float xs[8] = {a.x, a.y, a.z, a.w, d.x, d.y, d.z, d.w};
      #pragma unroll
      for (int j = 0; j < 8; ++j) {
        const uint32_t u = __float_as_uint(xs[j]);
        const float lf = xs[j] - __uint_as_float(u & 0xFFFF0000u);
        qhi[c][j] = (short)(u >> 16);
        qlo[c][j] = (short)(__float_as_uint(lf) >> 16);
      }
    }
  }

  f32x4 accO[8];
  #pragma unroll
  for (int i = 0; i < 8; ++i) accO[i] = (f32x4){0.f, 0.f, 0.f, 0.f};

  short* const pwv = &sP[w * 16 * PSTR];

  for (int kt = 0; kt < S_ / TK; ++kt) {
    __syncthreads();   // previous iter's reads done before overwriting tiles

    // ---- stage K tile as hi/lo bf16 (truncation split; lo exact residual) ----
    {
      const int krow = t >> 2, dseg = (t & 3) * 32;
      const float* gk = K + ((size_t)(b * S_ + kt * TK + krow)) * D_ + dseg;
      #pragma unroll
      for (int u8 = 0; u8 < 4; ++u8) {
        const float4 a = *(const float4*)(gk + u8 * 8);
        const float4 d = *(const float4*)(gk + u8 * 8 + 4);
        const float xs[8] = {a.x, a.y, a.z, a.w, d.x, d.y, d.z, d.w};
        b16x8 hi, lo;
        #pragma unroll
        for (int j = 0; j < 8; ++j) {
          const uint32_t u = __float_as_uint(xs[j]);
          const float lf = xs[j] - __uint_as_float(u & 0xFFFF0000u);
          hi[j] = (short)(u >> 16);
          lo[j] = (short)(__float_as_uint(lf) >> 16);
        }
        *(b16x8*)&sKhi[krow * KSTR + dseg + u8 * 8] = hi;
        *(b16x8*)&sKlo[krow * KSTR + dseg + u8 * 8] = lo;
      }
    }
    // ---- stage V transposed (RNE bf16), conflict-free packed b32 writes ----
    {
      const int kp2 = t & 31, dseg = (t >> 5) * 16;
      const float* g0 = V + ((size_t)(b * S_ + kt * TK + 2 * kp2)) * D_ + dseg;
      float v0[16], v1[16];
      #pragma unroll
      for (int u4 = 0; u4 < 4; ++u4) {
        *(float4*)&v0[u4 * 4] = *(const float4*)(g0 + u4 * 4);
        *(float4*)&v1[u4 * 4] = *(const float4*)(g0 + D_ + u4 * 4);
      }
      #pragma unroll
      for (int d = 0; d < 16; ++d) {
        const uint32_t pk = (uint32_t)bf16_rne(v0[d]) |
                            ((uint32_t)bf16_rne(v1[d]) << 16);
        *(uint32_t*)&sVT[(dseg + d) * VSTR + 2 * kp2] = pk;
      }
    }
    __syncthreads();

    // ---- QK^T: 16 q-rows x 64 keys, split-bf16 (3 products) ----
    f32x4 s[4];
    #pragma unroll
    for (int n = 0; n < 4; ++n) {
      f32x4 acc = (f32x4){0.f, 0.f, 0.f, 0.f};
      #pragma unroll
      for (int c = 0; c < 4; ++c) {
        const b16x8 bh = *(const b16x8*)&sKhi[(n * 16 + l15) * KSTR + c * 32 + quad * 8];
        const b16x8 bl = *(const b16x8*)&sKlo[(n * 16 + l15) * KSTR + c * 32 + quad * 8];
        acc = __builtin_amdgcn_mfma_f32_16x16x32_bf16(qhi[c], bh, acc, 0, 0, 0);
        acc = __builtin_amdgcn_mfma_f32_16x16x32_bf16(qhi[c], bl, acc, 0, 0, 0);
        acc = __builtin_amdgcn_mfma_f32_16x16x32_bf16(qlo[c], bh, acc, 0, 0, 0);
      }
      s[n] = acc;
    }

    // ---- scale + online softmax (row r lives in lanes of this quad) ----
    float mx[4];
    #pragma unroll
    for (int r = 0; r < 4; ++r) {
      s[0][r] *= rsc[r]; s[1][r] *= rsc[r]; s[2][r] *= rsc[r]; s[3][r] *= rsc[r];
      mx[r] = fmaxf(fmaxf(s[0][r], s[1][r]), fmaxf(s[2][r], s[3][r]));
    }
    #pragma unroll
    for (int off = 1; off < 16; off <<= 1) {
      #pragma unroll
      for (int r = 0; r < 4; ++r) mx[r] = fmaxf(mx[r], __shfl_xor(mx[r], off, 16));
    }
    float alpha[4], rs[4];
    #pragma unroll
    for (int r = 0; r < 4; ++r) {
      const float mnew = fmaxf(m_[r], mx[r]);
      alpha[r] = __expf(m_[r] - mnew);   // first iter: exp(-inf)=0
      m_[r] = mnew;
      rs[r] = 0.f;
    }
    #pragma unroll
    for (int n = 0; n < 4; ++n) {
      #pragma unroll
      for (int r = 0; r < 4; ++r) {
        const float p = __expf(s[n][r] - m_[r]);
        s[n][r] = p;
        rs[r] += p;
      }
    }
    #pragma unroll
    for (int off = 1; off < 16; off <<= 1) {
      #pragma unroll
      for (int r = 0; r < 4; ++r) rs[r] += __shfl_xor(rs[r], off, 16);
    }
    #pragma unroll
    for (int r = 0; r < 4; ++r) l_[r] = l_[r] * alpha[r] + rs[r];
    #pragma unroll
    for (int i = 0; i < 8; ++i) {
      #pragma unroll
      for (int r = 0; r < 4; ++r) accO[i][r] *= alpha[r];
    }

    // ---- dropout (exact threefry) + masked bf16 P into wave-private LDS ----
    #pragma unroll
    for (int n = 0; n < 4; ++n) {
      const int col = n * 16 + l15;
      #pragma unroll
      for (int r = 0; r < 4; ++r) {
        const uint32_t bits = jax_bits(jq[r] + (uint32_t)(kt * TK + col));
        const float uni = __uint_as_float((bits >> 9) | 0x3F800000u) - 1.0f;
        const uint16_t pb = bf16_rne(s[n][r]);
        pwv[(quad * 4 + r) * PSTR + col] = (uni < kp) ? (short)pb : (short)0;
      }
    }
    __threadfence_block();   // order cross-lane P writes before A-frag reads

    // ---- PV: O[16q x 128d] += P[16x64] * V[64x128] ----
    #pragma unroll
    for (int ks = 0; ks < 2; ++ks) {
      const b16x8 ap = *(const b16x8*)&pwv[l15 * PSTR + ks * 32 + quad * 8];
      #pragma unroll
      for (int d8 = 0; d8 < 8; ++d8) {
        const b16x8 bv = *(const b16x8*)&sVT[(d8 * 16 + l15) * VSTR + ks * 32 + quad * 8];
        accO[d8] = __builtin_amdgcn_mfma_f32_16x16x32_bf16(ap, bv, accO[d8], 0, 0, 0);
      }
    }
  }

  // ---- epilogue: O / (l * keep_prob) ----
  float inv[4];
  #pragma unroll
  for (int r = 0; r < 4; ++r) inv[r] = 1.0f / (l_[r] * kp);
  float* op = OUT + ((size_t)(b * S_ + qw)) * D_;
  #pragma unroll
  for (int d8 = 0; d8 < 8; ++d8) {
    #pragma unroll
    for (int r = 0; r < 4; ++r)
      op[(quad * 4 + r) * D_ + d8 * 16 + l15] = accO[d8][r] * inv[r];
  }
}

extern "C" void kernel_launch(void* const* d_in, const int* in_sizes, int n_in,
                              void* d_out, int out_size, void* d_ws, size_t ws_size,
                              hipStream_t stream) {
  const float* q   = (const float*)d_in[0];
  const float* k   = (const float*)d_in[1];
  const float* v   = (const float*)d_in[2];
  const float* isf = (const float*)d_in[3];
  const float* dp  = (const float*)d_in[4];
  float* out = (float*)d_out;

  dim3 grid(S_ / TQ, B_);
  attn_mfma_kernel<<<grid, dim3(256), 0, stream>>>(q, k, v, isf, dp, out);
}

// Round 4
// 342.420 us; speedup vs baseline: 3.1736x; 1.0080x over previous
//
#include <hip/hip_runtime.h>
#include <hip/hip_bf16.h>
#include <stdint.h>

// B=16, S=2048, D=128 attention, per-query scale folded into Q, online
// softmax, exact JAX partitionable-threefry dropout (key 42, p=0.1), @V.
// Split-bf16 QK^T (3 MFMA products), bf16 P/V for PV.
// Round 4: register-prefetch pipeline for K/V staging (hide HBM latency
// behind compute; vmcnt drain at barrier lands after full compute phase),
// hw packed bf16 converts, integer-domain dropout compare.

#define B_ 16
#define S_ 2048
#define D_ 128
#define TQ 64     // q rows per block (4 waves x 16)
#define TK 64     // keys per iteration
#define KSTR 136  // bf16 stride for K rows (128+8)
#define VSTR 72   // bf16 stride for V^T rows (64+8)
#define PSTR 72   // bf16 stride for P rows

typedef float f32x4 __attribute__((ext_vector_type(4)));
typedef short b16x8 __attribute__((ext_vector_type(8)));

union U4B8 { uint32_t u[4]; b16x8 v; };
union F32R { float4 q[8]; float f[32]; };
union F16R { float4 q[4]; float f[16]; };

__device__ __forceinline__ uint32_t pk_bf16(float a, float b) {
  union { __hip_bfloat162 h; uint32_t u; } c;
  c.h = __float22bfloat162_rn(make_float2(a, b));   // a -> low 16, b -> high 16
  return c.u;
}

// threefry2x32, 20 rounds, key = (0, 42)  [jax.random.key(42)]
__device__ __forceinline__ uint2 threefry2x32_0_42(uint32_t x0, uint32_t x1) {
  const uint32_t k0 = 0u, k1 = 42u;
  const uint32_t k2 = 0x1BD11BDAu ^ k0 ^ k1;
  x0 += k0; x1 += k1;
#define TFR(r) { x0 += x1; x1 = (x1 << (r)) | (x1 >> (32 - (r))); x1 ^= x0; }
  TFR(13) TFR(15) TFR(26) TFR(6)
  x0 += k1; x1 += k2 + 1u;
  TFR(17) TFR(29) TFR(16) TFR(24)
  x0 += k2; x1 += k0 + 2u;
  TFR(13) TFR(15) TFR(26) TFR(6)
  x0 += k0; x1 += k1 + 3u;
  TFR(17) TFR(29) TFR(16) TFR(24)
  x0 += k1; x1 += k2 + 4u;
  TFR(13) TFR(15) TFR(26) TFR(6)
  x0 += k2; x1 += k0 + 5u;
#undef TFR
  return make_uint2(x0, x1);
}

// HW-verified (round 2): partitionable path, counter (0, j), xor-fold.
__device__ __forceinline__ uint32_t jax_bits(uint32_t j) {
  const uint2 tf = threefry2x32_0_42(0u, j);
  return tf.x ^ tf.y;
}

__global__ __launch_bounds__(256, 2)
void attn_mfma_kernel(const float* __restrict__ Q, const float* __restrict__ K,
                      const float* __restrict__ V, const float* __restrict__ ISF,
                      const float* __restrict__ DP, float* __restrict__ OUT) {
  __shared__ __align__(16) short sKhi[TK * KSTR];
  __shared__ __align__(16) short sKlo[TK * KSTR];
  __shared__ __align__(16) short sVT[D_ * VSTR];
  __shared__ __align__(16) short sP[4 * 16 * PSTR];   // per-wave 16x72

  const int t    = threadIdx.x;
  const int w    = t >> 6;
  const int lane = t & 63;
  const int l15  = lane & 15;
  const int quad = lane >> 4;
  const int b    = blockIdx.y;
  const int qw   = blockIdx.x * TQ + w * 16;   // wave's first q row

  const float kp = 1.0f - DP[0];
  // integer dropout threshold: keep <=> (bits>>9) < TH   (1+kp exact in fp32)
  const uint32_t TH = __float_as_uint(1.0f + kp) & 0x7FFFFFu;

  float m_[4], l_[4];
  uint32_t jq[4];
  #pragma unroll
  for (int r = 0; r < 4; ++r) {
    m_[r] = -INFINITY;
    l_[r] = 0.0f;
    jq[r] = ((uint32_t)b << 22) + (uint32_t)(qw + quad * 4 + r) * (uint32_t)S_;
  }

  // ---- Q fragments (hi/lo split), per-query scale folded in ----
  b16x8 qhi[4], qlo[4];
  {
    const float qs = 1.0f / ISF[b * S_ + qw + l15];   // row m = l15 of A-frag
    const float* qp = Q + ((size_t)(b * S_ + qw + l15)) * D_;
    #pragma unroll
    for (int c = 0; c < 4; ++c) {
      const float4 a = *(const float4*)(qp + c * 32 + quad * 8);
      const float4 d = *(const float4*)(qp + c * 32 + quad * 8 + 4);
      float xs[8] = {a.x, a.y, a.z, a.w, d.x, d.y, d.z, d.w};
      U4B8 hi, lo;
      #pragma unroll
      for (int p = 0; p < 4; ++p) {
        const float x0 = xs[2 * p] * qs, x1 = xs[2 * p + 1] * qs;
        const uint32_t h = pk_bf16(x0, x1);
        const float r0 = x0 - __uint_as_float(h << 16);
        const float r1 = x1 - __uint_as_float(h & 0xFFFF0000u);
        hi.u[p] = h;
        lo.u[p] = pk_bf16(r0, r1);
      }
      qhi[c] = hi.v;
      qlo[c] = lo.v;
    }
  }

  f32x4 accO[8];
  #pragma unroll
  for (int i = 0; i < 8; ++i) accO[i] = (f32x4){0.f, 0.f, 0.f, 0.f};

  short* const pwv = &sP[w * 16 * PSTR];

  // staging decomposition (256 threads)
  const int krow = t >> 2, kcol = (t & 3) * 32;        // K: 64 rows x 128
  const int vkey = 2 * (t & 31), vseg = (t >> 5) * 16; // V: key pairs x 16 d

  F32R kreg;            // prefetched K floats (32/thread)
  F16R vreg0, vreg1;    // prefetched V floats (16+16/thread)

#define ISSUE_LOADS(KT)                                                        \
  {                                                                            \
    const float4* gk4 = (const float4*)(K +                                    \
        ((size_t)(b * S_ + (KT) * TK + krow)) * D_ + kcol);                    \
    _Pragma("unroll") for (int i = 0; i < 8; ++i) kreg.q[i] = gk4[i];          \
    const float4* gv4 = (const float4*)(V +                                    \
        ((size_t)(b * S_ + (KT) * TK + vkey)) * D_ + vseg);                    \
    _Pragma("unroll") for (int i = 0; i < 4; ++i) {                            \
      vreg0.q[i] = gv4[i];                                                     \
      vreg1.q[i] = gv4[i + 32];  /* +128 floats = next key row */              \
    }                                                                          \
  }

  ISSUE_LOADS(0)

  for (int kt = 0; kt < S_ / TK; ++kt) {
    __syncthreads();   // A: prev iter's tile reads done; prefetch drained here

    // ---- convert prefetched K (RNE-hi + exact residual lo) -> LDS ----
    {
      short* kh = &sKhi[krow * KSTR + kcol];
      short* kl = &sKlo[krow * KSTR + kcol];
      #pragma unroll
      for (int g = 0; g < 4; ++g) {
        U4B8 hi, lo;
        #pragma unroll
        for (int p = 0; p < 4; ++p) {
          const float x0 = kreg.f[g * 8 + 2 * p], x1 = kreg.f[g * 8 + 2 * p + 1];
          const uint32_t h = pk_bf16(x0, x1);
          const float r0 = x0 - __uint_as_float(h << 16);
          const float r1 = x1 - __uint_as_float(h & 0xFFFF0000u);
          hi.u[p] = h;
          lo.u[p] = pk_bf16(r0, r1);
        }
        *(b16x8*)&kh[g * 8] = hi.v;
        *(b16x8*)&kl[g * 8] = lo.v;
      }
    }
    // ---- convert prefetched V -> transposed bf16 LDS (packed b32) ----
    {
      #pragma unroll
      for (int d = 0; d < 16; ++d)
        *(uint32_t*)&sVT[(vseg + d) * VSTR + vkey] = pk_bf16(vreg0.f[d], vreg1.f[d]);
    }
    __syncthreads();   // B: tile kt visible

    // ---- prefetch tile kt+1 into registers (latency hidden by compute) ----
    if (kt + 1 < S_ / TK) ISSUE_LOADS(kt + 1)

    // ---- QK^T: 16 q-rows x 64 keys, split-bf16 (3 products) ----
    f32x4 s[4];
    #pragma unroll
    for (int n = 0; n < 4; ++n) {
      f32x4 acc = (f32x4){0.f, 0.f, 0.f, 0.f};
      #pragma unroll
      for (int c = 0; c < 4; ++c) {
        const b16x8 bh = *(const b16x8*)&sKhi[(n * 16 + l15) * KSTR + c * 32 + quad * 8];
        const b16x8 bl = *(const b16x8*)&sKlo[(n * 16 + l15) * KSTR + c * 32 + quad * 8];
        acc = __builtin_amdgcn_mfma_f32_16x16x32_bf16(qhi[c], bh, acc, 0, 0, 0);
        acc = __builtin_amdgcn_mfma_f32_16x16x32_bf16(qhi[c], bl, acc, 0, 0, 0);
        acc = __builtin_amdgcn_mfma_f32_16x16x32_bf16(qlo[c], bh, acc, 0, 0, 0);
      }
      s[n] = acc;
    }

    // ---- online softmax (row r of this quad across 16 lanes) ----
    float mx[4];
    #pragma unroll
    for (int r = 0; r < 4; ++r)
      mx[r] = fmaxf(fmaxf(s[0][r], s[1][r]), fmaxf(s[2][r], s[3][r]));
    #pragma unroll
    for (int off = 1; off < 16; off <<= 1) {
      #pragma unroll
      for (int r = 0; r < 4; ++r) mx[r] = fmaxf(mx[r], __shfl_xor(mx[r], off, 16));
    }
    float alpha[4], rs[4];
    #pragma unroll
    for (int r = 0; r < 4; ++r) {
      const float mnew = fmaxf(m_[r], mx[r]);
      alpha[r] = __expf(m_[r] - mnew);   // first iter: exp(-inf)=0
      m_[r] = mnew;
      rs[r] = 0.f;
    }
    #pragma unroll
    for (int n = 0; n < 4; ++n) {
      #pragma unroll
      for (int r = 0; r < 4; ++r) {
        const float p = __expf(s[n][r] - m_[r]);
        s[n][r] = p;
        rs[r] += p;
      }
    }
    #pragma unroll
    for (int off = 1; off < 16; off <<= 1) {
      #pragma unroll
      for (int r = 0; r < 4; ++r) rs[r] += __shfl_xor(rs[r], off, 16);
    }
    #pragma unroll
    for (int r = 0; r < 4; ++r) l_[r] = l_[r] * alpha[r] + rs[r];
    #pragma unroll
    for (int i = 0; i < 8; ++i) {
      #pragma unroll
      for (int r = 0; r < 4; ++r) accO[i][r] *= alpha[r];
    }

    // ---- dropout (exact threefry, integer compare) + bf16 P to LDS ----
    #pragma unroll
    for (int n = 0; n < 4; ++n) {
      const int col = n * 16 + l15;
      const uint32_t jcol = (uint32_t)(kt * TK + col);
      float pf[4];
      #pragma unroll
      for (int r = 0; r < 4; ++r) {
        const uint32_t bits = jax_bits(jq[r] + jcol);
        pf[r] = ((bits >> 9) < TH) ? s[n][r] : 0.0f;
      }
      const uint32_t pk01 = pk_bf16(pf[0], pf[1]);
      const uint32_t pk23 = pk_bf16(pf[2], pf[3]);
      pwv[(quad * 4 + 0) * PSTR + col] = (short)(uint16_t)pk01;
      pwv[(quad * 4 + 1) * PSTR + col] = (short)(uint16_t)(pk01 >> 16);
      pwv[(quad * 4 + 2) * PSTR + col] = (short)(uint16_t)pk23;
      pwv[(quad * 4 + 3) * PSTR + col] = (short)(uint16_t)(pk23 >> 16);
    }
    __threadfence_block();   // order cross-lane P writes before A-frag reads

    // ---- PV: O[16 x 128] += P[16 x 64] * V[64 x 128] ----
    #pragma unroll
    for (int ks = 0; ks < 2; ++ks) {
      const b16x8 ap = *(const b16x8*)&pwv[l15 * PSTR + ks * 32 + quad * 8];
      #pragma unroll
      for (int d8 = 0; d8 < 8; ++d8) {
        const b16x8 bv = *(const b16x8*)&sVT[(d8 * 16 + l15) * VSTR + ks * 32 + quad * 8];
        accO[d8] = __builtin_amdgcn_mfma_f32_16x16x32_bf16(ap, bv, accO[d8], 0, 0, 0);
      }
    }
  }
#undef ISSUE_LOADS

  // ---- epilogue: O / (l * keep_prob) ----
  float inv[4];
  #pragma unroll
  for (int r = 0; r < 4; ++r) inv[r] = 1.0f / (l_[r] * kp);
  float* op = OUT + ((size_t)(b * S_ + qw)) * D_;
  #pragma unroll
  for (int d8 = 0; d8 < 8; ++d8) {
    #pragma unroll
    for (int r = 0; r < 4; ++r)
      op[(quad * 4 + r) * D_ + d8 * 16 + l15] = accO[d8][r] * inv[r];
  }
}

extern "C" void kernel_launch(void* const* d_in, const int* in_sizes, int n_in,
                              void* d_out, int out_size, void* d_ws, size_t ws_size,
                              hipStream_t stream) {
  const float* q   = (const float*)d_in[0];
  const float* k   = (const float*)d_in[1];
  const float* v   = (const float*)d_in[2];
  const float* isf = (const float*)d_in[3];
  const float* dp  = (const float*)d_in[4];
  float* out = (float*)d_out;

  dim3 grid(S_ / TQ, B_);
  attn_mfma_kernel<<<grid, dim3(256), 0, stream>>>(q, k, v, isf, dp, out);
}

// Round 5
// 330.718 us; speedup vs baseline: 3.2859x; 1.0354x over previous
//
#include <hip/hip_runtime.h>
#include <hip/hip_bf16.h>
#include <stdint.h>

// B=16, S=2048, D=128 attention, per-query scale folded into Q (with log2e),
// online softmax in exp2 domain, exact JAX partitionable-threefry dropout
// (key 42, p=0.1), @V.  Split-bf16 QK^T (3 MFMA), bf16 P/V for PV.
// Round 5: rotateleft threefry (v_alignbit), shiftless dropout compare,
// DPP row_ror softmax reductions (off the DS pipe), alpha-skip rescale.

#define B_ 16
#define S_ 2048
#define D_ 128
#define TQ 64     // q rows per block (4 waves x 16)
#define TK 64     // keys per iteration
#define KSTR 136  // bf16 stride for K rows (128+8)
#define VSTR 72   // bf16 stride for V^T rows (64+8)
#define PSTR 72   // bf16 stride for P rows

typedef float f32x4 __attribute__((ext_vector_type(4)));
typedef short b16x8 __attribute__((ext_vector_type(8)));

union U4B8 { uint32_t u[4]; b16x8 v; };
union F32R { float4 q[8]; float f[32]; };
union F16R { float4 q[4]; float f[16]; };

__device__ __forceinline__ uint32_t pk_bf16(float a, float b) {
  union { __hip_bfloat162 h; uint32_t u; } c;
  c.h = __float22bfloat162_rn(make_float2(a, b));   // a -> low 16, b -> high 16
  return c.u;
}

// DPP row_ror helpers: reduce over the 16 lanes of a row (our quad group).
#define DPP_ROR(x, ctrl) \
  __int_as_float(__builtin_amdgcn_update_dpp(0, __float_as_int(x), (ctrl), 0xf, 0xf, true))
__device__ __forceinline__ float row16_max(float x) {
  x = fmaxf(x, DPP_ROR(x, 0x128));   // ror 8
  x = fmaxf(x, DPP_ROR(x, 0x124));   // ror 4
  x = fmaxf(x, DPP_ROR(x, 0x122));   // ror 2
  x = fmaxf(x, DPP_ROR(x, 0x121));   // ror 1
  return x;
}
__device__ __forceinline__ float row16_sum(float x) {
  x += DPP_ROR(x, 0x128);
  x += DPP_ROR(x, 0x124);
  x += DPP_ROR(x, 0x122);
  x += DPP_ROR(x, 0x121);
  return x;
}

// threefry2x32, 20 rounds, key = (0, 42)  [jax.random.key(42)]
__device__ __forceinline__ uint2 threefry2x32_0_42(uint32_t x0, uint32_t x1) {
  const uint32_t k0 = 0u, k1 = 42u;
  const uint32_t k2 = 0x1BD11BDAu ^ k0 ^ k1;
  x0 += k0; x1 += k1;
#define TFR(r) { x0 += x1; x1 = __builtin_rotateleft32(x1, r); x1 ^= x0; }
  TFR(13) TFR(15) TFR(26) TFR(6)
  x0 += k1; x1 += k2 + 1u;
  TFR(17) TFR(29) TFR(16) TFR(24)
  x0 += k2; x1 += k0 + 2u;
  TFR(13) TFR(15) TFR(26) TFR(6)
  x0 += k0; x1 += k1 + 3u;
  TFR(17) TFR(29) TFR(16) TFR(24)
  x0 += k1; x1 += k2 + 4u;
  TFR(13) TFR(15) TFR(26) TFR(6)
  x0 += k2; x1 += k0 + 5u;
#undef TFR
  return make_uint2(x0, x1);
}

// HW-verified (round 2): partitionable path, counter (0, j), xor-fold.
__device__ __forceinline__ uint32_t jax_bits(uint32_t j) {
  const uint2 tf = threefry2x32_0_42(0u, j);
  return tf.x ^ tf.y;
}

__global__ __launch_bounds__(256, 2)
void attn_mfma_kernel(const float* __restrict__ Q, const float* __restrict__ K,
                      const float* __restrict__ V, const float* __restrict__ ISF,
                      const float* __restrict__ DP, float* __restrict__ OUT) {
  __shared__ __align__(16) short sKhi[TK * KSTR];
  __shared__ __align__(16) short sKlo[TK * KSTR];
  __shared__ __align__(16) short sVT[D_ * VSTR];
  __shared__ __align__(16) short sP[4 * 16 * PSTR];   // per-wave 16x72

  const int t    = threadIdx.x;
  const int w    = t >> 6;
  const int lane = t & 63;
  const int l15  = lane & 15;
  const int quad = lane >> 4;
  const int b    = blockIdx.y;
  const int qw   = blockIdx.x * TQ + w * 16;   // wave's first q row

  const float kp = 1.0f - DP[0];
  // keep <=> random_bits < TH9   (shiftless form of (bits>>9) < mant(1+kp))
  const uint32_t TH9 = (__float_as_uint(1.0f + kp) & 0x7FFFFFu) << 9;

  float m_[4], l_[4];
  uint32_t jq[4];
  #pragma unroll
  for (int r = 0; r < 4; ++r) {
    m_[r] = -INFINITY;
    l_[r] = 0.0f;
    jq[r] = ((uint32_t)b << 22) + (uint32_t)(qw + quad * 4 + r) * (uint32_t)S_;
  }

  // ---- Q fragments (hi/lo split); fold per-query 1/isf AND log2(e) in ----
  b16x8 qhi[4], qlo[4];
  {
    const float qs = 1.4426950408889634f / ISF[b * S_ + qw + l15];
    const float* qp = Q + ((size_t)(b * S_ + qw + l15)) * D_;
    #pragma unroll
    for (int c = 0; c < 4; ++c) {
      const float4 a = *(const float4*)(qp + c * 32 + quad * 8);
      const float4 d = *(const float4*)(qp + c * 32 + quad * 8 + 4);
      float xs[8] = {a.x, a.y, a.z, a.w, d.x, d.y, d.z, d.w};
      U4B8 hi, lo;
      #pragma unroll
      for (int p = 0; p < 4; ++p) {
        const float x0 = xs[2 * p] * qs, x1 = xs[2 * p + 1] * qs;
        const uint32_t h = pk_bf16(x0, x1);
        const float r0 = x0 - __uint_as_float(h << 16);
        const float r1 = x1 - __uint_as_float(h & 0xFFFF0000u);
        hi.u[p] = h;
        lo.u[p] = pk_bf16(r0, r1);
      }
      qhi[c] = hi.v;
      qlo[c] = lo.v;
    }
  }

  f32x4 accO[8];
  #pragma unroll
  for (int i = 0; i < 8; ++i) accO[i] = (f32x4){0.f, 0.f, 0.f, 0.f};

  short* const pwv = &sP[w * 16 * PSTR];

  // staging decomposition (256 threads)
  const int krow = t >> 2, kcol = (t & 3) * 32;        // K: 64 rows x 128
  const int vkey = 2 * (t & 31), vseg = (t >> 5) * 16; // V: key pairs x 16 d

  F32R kreg;            // prefetched K floats (32/thread)
  F16R vreg0, vreg1;    // prefetched V floats (16+16/thread)

#define ISSUE_LOADS(KT)                                                        \
  {                                                                            \
    const float4* gk4 = (const float4*)(K +                                    \
        ((size_t)(b * S_ + (KT) * TK + krow)) * D_ + kcol);                    \
    _Pragma("unroll") for (int i = 0; i < 8; ++i) kreg.q[i] = gk4[i];          \
    const float4* gv4 = (const float4*)(V +                                    \
        ((size_t)(b * S_ + (KT) * TK + vkey)) * D_ + vseg);                    \
    _Pragma("unroll") for (int i = 0; i < 4; ++i) {                            \
      vreg0.q[i] = gv4[i];                                                     \
      vreg1.q[i] = gv4[i + 32];  /* +128 floats = next key row */              \
    }                                                                          \
  }

  ISSUE_LOADS(0)

  for (int kt = 0; kt < S_ / TK; ++kt) {
    __syncthreads();   // A: prev iter's tile reads done

    // ---- convert prefetched K (RNE-hi + exact residual lo) -> LDS ----
    {
      short* kh = &sKhi[krow * KSTR + kcol];
      short* kl = &sKlo[krow * KSTR + kcol];
      #pragma unroll
      for (int g = 0; g < 4; ++g) {
        U4B8 hi, lo;
        #pragma unroll
        for (int p = 0; p < 4; ++p) {
          const float x0 = kreg.f[g * 8 + 2 * p], x1 = kreg.f[g * 8 + 2 * p + 1];
          const uint32_t h = pk_bf16(x0, x1);
          const float r0 = x0 - __uint_as_float(h << 16);
          const float r1 = x1 - __uint_as_float(h & 0xFFFF0000u);
          hi.u[p] = h;
          lo.u[p] = pk_bf16(r0, r1);
        }
        *(b16x8*)&kh[g * 8] = hi.v;
        *(b16x8*)&kl[g * 8] = lo.v;
      }
    }
    // ---- convert prefetched V -> transposed bf16 LDS (packed b32) ----
    {
      #pragma unroll
      for (int d = 0; d < 16; ++d)
        *(uint32_t*)&sVT[(vseg + d) * VSTR + vkey] = pk_bf16(vreg0.f[d], vreg1.f[d]);
    }
    __syncthreads();   // B: tile kt visible

    // ---- prefetch tile kt+1 into registers ----
    if (kt + 1 < S_ / TK) ISSUE_LOADS(kt + 1)

    // ---- QK^T: 16 q-rows x 64 keys, split-bf16 (3 products) ----
    f32x4 s[4];
    #pragma unroll
    for (int n = 0; n < 4; ++n) {
      f32x4 acc = (f32x4){0.f, 0.f, 0.f, 0.f};
      #pragma unroll
      for (int c = 0; c < 4; ++c) {
        const b16x8 bh = *(const b16x8*)&sKhi[(n * 16 + l15) * KSTR + c * 32 + quad * 8];
        const b16x8 bl = *(const b16x8*)&sKlo[(n * 16 + l15) * KSTR + c * 32 + quad * 8];
        acc = __builtin_amdgcn_mfma_f32_16x16x32_bf16(qhi[c], bh, acc, 0, 0, 0);
        acc = __builtin_amdgcn_mfma_f32_16x16x32_bf16(qhi[c], bl, acc, 0, 0, 0);
        acc = __builtin_amdgcn_mfma_f32_16x16x32_bf16(qlo[c], bh, acc, 0, 0, 0);
      }
      s[n] = acc;
    }

    // ---- online softmax in exp2 domain (row r = 16 lanes of this quad) ----
    float mx[4];
    #pragma unroll
    for (int r = 0; r < 4; ++r) {
      mx[r] = row16_max(fmaxf(fmaxf(s[0][r], s[1][r]), fmaxf(s[2][r], s[3][r])));
    }
    // wave-uniform alpha-skip: rescale only if some row's max grew
    int changed = 0;
    #pragma unroll
    for (int r = 0; r < 4; ++r) changed |= (mx[r] > m_[r]);
    if (__ballot(changed) != 0ull) {
      #pragma unroll
      for (int r = 0; r < 4; ++r) {
        const float mnew = fmaxf(m_[r], mx[r]);
        const float alpha = __builtin_amdgcn_exp2f(m_[r] - mnew);  // exp2(-inf)=0
        m_[r] = mnew;
        l_[r] *= alpha;
        #pragma unroll
        for (int i = 0; i < 8; ++i) accO[i][r] *= alpha;
      }
    }
    float rs[4];
    #pragma unroll
    for (int r = 0; r < 4; ++r) {
      float lr = 0.f;
      #pragma unroll
      for (int n = 0; n < 4; ++n) {
        const float p = __builtin_amdgcn_exp2f(s[n][r] - m_[r]);
        s[n][r] = p;
        lr += p;
      }
      rs[r] = lr;
    }
    #pragma unroll
    for (int r = 0; r < 4; ++r) l_[r] += row16_sum(rs[r]);

    // ---- dropout (exact threefry, shiftless compare) + bf16 P to LDS ----
    #pragma unroll
    for (int n = 0; n < 4; ++n) {
      const int col = n * 16 + l15;
      const uint32_t jcol = (uint32_t)(kt * TK + col);
      float pf[4];
      #pragma unroll
      for (int r = 0; r < 4; ++r) {
        const uint32_t bits = jax_bits(jq[r] + jcol);
        pf[r] = (bits < TH9) ? s[n][r] : 0.0f;
      }
      const uint32_t pk01 = pk_bf16(pf[0], pf[1]);
      const uint32_t pk23 = pk_bf16(pf[2], pf[3]);
      pwv[(quad * 4 + 0) * PSTR + col] = (short)(uint16_t)pk01;
      pwv[(quad * 4 + 1) * PSTR + col] = (short)(uint16_t)(pk01 >> 16);
      pwv[(quad * 4 + 2) * PSTR + col] = (short)(uint16_t)pk23;
      pwv[(quad * 4 + 3) * PSTR + col] = (short)(uint16_t)(pk23 >> 16);
    }
    __threadfence_block();   // order cross-lane P writes before A-frag reads

    // ---- PV: O[16 x 128] += P[16 x 64] * V[64 x 128] ----
    #pragma unroll
    for (int ks = 0; ks < 2; ++ks) {
      const b16x8 ap = *(const b16x8*)&pwv[l15 * PSTR + ks * 32 + quad * 8];
      #pragma unroll
      for (int d8 = 0; d8 < 8; ++d8) {
        const b16x8 bv = *(const b16x8*)&sVT[(d8 * 16 + l15) * VSTR + ks * 32 + quad * 8];
        accO[d8] = __builtin_amdgcn_mfma_f32_16x16x32_bf16(ap, bv, accO[d8], 0, 0, 0);
      }
    }
  }
#undef ISSUE_LOADS

  // ---- epilogue: O / (l * keep_prob) ----
  float inv[4];
  #pragma unroll
  for (int r = 0; r < 4; ++r) inv[r] = 1.0f / (l_[r] * kp);
  float* op = OUT + ((size_t)(b * S_ + qw)) * D_;
  #pragma unroll
  for (int d8 = 0; d8 < 8; ++d8) {
    #pragma unroll
    for (int r = 0; r < 4; ++r)
      op[(quad * 4 + r) * D_ + d8 * 16 + l15] = accO[d8][r] * inv[r];
  }
}

extern "C" void kernel_launch(void* const* d_in, const int* in_sizes, int n_in,
                              void* d_out, int out_size, void* d_ws, size_t ws_size,
                              hipStream_t stream) {
  const float* q   = (const float*)d_in[0];
  const float* k   = (const float*)d_in[1];
  const float* v   = (const float*)d_in[2];
  const float* isf = (const float*)d_in[3];
  const float* dp  = (const float*)d_in[4];
  float* out = (float*)d_out;

  dim3 grid(S_ / TQ, B_);
  attn_mfma_kernel<<<grid, dim3(256), 0, stream>>>(q, k, v, isf, dp, out);
}